// Round 11
// baseline (189.809 us; speedup 1.0000x reference)
//
#include <hip/hip_runtime.h>

typedef unsigned short u16;
typedef unsigned int u32;
typedef __attribute__((ext_vector_type(8))) short bf16x8;
typedef __attribute__((ext_vector_type(4))) float f32x4;

__device__ __forceinline__ u16 f2bf(float f) {
    u32 u = __builtin_bit_cast(u32, f);
    u += 0x7FFFu + ((u >> 16) & 1u);
    return (u16)(u >> 16);
}
__device__ __forceinline__ float bf2f(u16 s) {
    u32 u = ((u32)s) << 16;
    return __builtin_bit_cast(float, u);
}
__device__ __forceinline__ float sigm(float x) {
    return 1.0f / (1.0f + __expf(-x));
}
__device__ __forceinline__ void gload16(const u16* g, u16* l) {
    __builtin_amdgcn_global_load_lds(
        (const __attribute__((address_space(1))) void*)g,
        (__attribute__((address_space(3))) void*)l, 16, 0, 0);
}

// ---------------- P1: x (B,C,H,W) fp32 -> x' [p][c] bf16, p=(b*64+h)*64+w ----
__global__ __launch_bounds__(256) void transpose_in(const float* __restrict__ x,
                                                    u16* __restrict__ xp) {
    __shared__ float tile[64][65];
    int bid = blockIdx.x;
    int ct = bid & 3, h = (bid >> 2) & 63, b = bid >> 8;
    int t = threadIdx.x;
    int tr = t >> 4, tc = t & 15;
    const float* src = x + (((size_t)(b * 256 + ct * 64) * 64 + h) * 64);
#pragma unroll
    for (int i = 0; i < 4; ++i) {
        int c = tr + i * 16;
        float4 v = *(const float4*)(src + (size_t)c * 4096 + tc * 4);
        tile[c][tc * 4 + 0] = v.x;
        tile[c][tc * 4 + 1] = v.y;
        tile[c][tc * 4 + 2] = v.z;
        tile[c][tc * 4 + 3] = v.w;
    }
    __syncthreads();
    u16* dst = xp + ((size_t)((b * 64 + h) * 64)) * 256 + ct * 64;
#pragma unroll
    for (int i = 0; i < 4; ++i) {
        int w = tr + i * 16;
        ushort4 o;
        o.x = f2bf(tile[tc * 4 + 0][w]);
        o.y = f2bf(tile[tc * 4 + 1][w]);
        o.z = f2bf(tile[tc * 4 + 2][w]);
        o.w = f2bf(tile[tc * 4 + 3][w]);
        *(ushort4*)(dst + (size_t)w * 256 + tc * 4) = o;
    }
}

// ---------------- weight prep: split q / key(row-major) / val+fus(permuted) --
// Permuted layout: W'[k>>3][outch][k&7]  (16B unit = 8 consecutive k of one ch)
// -> global_load_lds staging of a [4][256][8] k-tile is perfectly linear.
__global__ __launch_bounds__(256) void prep_w(const float* __restrict__ qw,
                                              const float* __restrict__ qb,
                                              const float* __restrict__ fw,
                                              const float* __restrict__ fb,
                                              float* __restrict__ wq0,
                                              u16* __restrict__ wkvK,
                                              u16* __restrict__ wkvV,
                                              float* __restrict__ bkv,
                                              u16* __restrict__ wfP,
                                              float* __restrict__ bff) {
    int i = blockIdx.x * 256 + threadIdx.x;
    if (i < 513 * 256) {
        int o = i >> 8, c = i & 255;
        float v = qw[i];
        if (o == 0)        wq0[c] = v;
        else if (o < 257)  wkvK[(size_t)(o - 1) * 256 + c] = f2bf(v);
        else               wkvV[(c >> 3) * 2048 + (o - 257) * 8 + (c & 7)] = f2bf(v);
    }
    if (i < 65536) {
        int o = i >> 8, c = i & 255;
        wfP[(c >> 3) * 2048 + o * 8 + (c & 7)] = f2bf(fw[i]);
    }
    if (i < 512) bkv[i] = qb[i + 1];
    if (i < 256) bff[i] = fb[i];
}

// ---------------- line_ctx: per-line q-dot + softmax + y = sc^T X + ----------
// ----------------           ctx = Wk*y + bk  (ctx out, 1 block per line) -----
template <int AXIS>
__global__ __launch_bounds__(256) void line_ctx(
    const u16* __restrict__ A, const u16* __restrict__ Wk,
    const float* __restrict__ wq0, const float* __restrict__ bkv,
    float* __restrict__ ctx) {
    __shared__ alignas(16) u16 Xl[64 * 256];
    __shared__ float ql[64];
    __shared__ float sc[64];
    __shared__ alignas(16) float ys[256];
    int t = threadIdx.x, lane = t & 63, wv = t >> 6;
    int l = blockIdx.x;
    auto prow = [&](int r) -> size_t {
        if (AXIS == 0) return (size_t)l * 64 + r;
        else           return (size_t)(l >> 6) * 4096 + (size_t)r * 64 + (l & 63);
    };
#pragma unroll
    for (int i = 0; i < 8; ++i) {
        int row = i * 8 + wv * 2 + (lane >> 5);
        int slot = (lane & 31) ^ (row & 7);
        gload16(A + prow(row) * 256 + slot * 8, &Xl[(i * 8 + wv * 2) * 256]);
    }
    __syncthreads();
    {
        int row = t >> 2, g = t & 3;
        const float* wp = wq0 + g * 64;
        float a = 0.f;
#pragma unroll
        for (int cc = 0; cc < 8; ++cc) {
            int slot = (g * 8 + cc) ^ (row & 7);
            bf16x8 v = *(const bf16x8*)&Xl[row * 256 + slot * 8];
#pragma unroll
            for (int j = 0; j < 8; ++j) a += bf2f((u16)v[j]) * wp[cc * 8 + j];
        }
        a += __shfl_xor(a, 1);
        a += __shfl_xor(a, 2);
        if (g == 0) ql[row] = a;
    }
    __syncthreads();
    if (t < 64) {
        float qv = ql[t];
        float m = qv;
#pragma unroll
        for (int off = 32; off > 0; off >>= 1) m = fmaxf(m, __shfl_xor(m, off));
        float e = __expf(qv - m);
        float s = e;
#pragma unroll
        for (int off = 32; off > 0; off >>= 1) s += __shfl_xor(s, off);
        sc[t] = e / s;
    }
    __syncthreads();
    {
        int chunk = t >> 3, e7 = t & 7;
        float a = 0.f;
#pragma unroll 8
        for (int p = 0; p < 64; ++p) {
            int slot = chunk ^ (p & 7);
            a += bf2f(Xl[p * 256 + slot * 8 + e7]) * sc[p];
        }
        ys[t] = a;
    }
    __syncthreads();
    {
        const u16* wk = Wk + (size_t)t * 256;
        float a = 0.f;
#pragma unroll
        for (int kc = 0; kc < 32; ++kc) {
            bf16x8 w = *(const bf16x8*)(wk + kc * 8);
#pragma unroll
            for (int j = 0; j < 8; ++j) a += bf2f((u16)w[j]) * ys[kc * 8 + j];
        }
        ctx[(size_t)l * 256 + t] = a + bkv[t];
    }
}

// ---------------- fused_stage: val GEMM + gate (in LDS) + fusion GEMM --------
// Block = 128 consecutive p rows, all 256 channels. 512 threads (8 waves):
// wave = rowhalf(wv>>2) x 64-ch slab(wv&3). LDS = X/G panel 64KB + W k-tile
// 16KB = exactly 80KB -> 2 blocks/CU. G never touches global memory.
// MODE 1: bf16 [p][ch] out (swapped fusion). MODE 2: fp32 (b,c,hw) out (normal).
template <int AXIS, int MODE>
__global__ __launch_bounds__(512, 2) void fused_stage(
    const u16* __restrict__ A, const u16* __restrict__ WvP,
    const float* __restrict__ bv, const u16* __restrict__ WfP,
    const float* __restrict__ bfb, const float* __restrict__ ctx,
    u16* __restrict__ bOut, float* __restrict__ fOut) {
    __shared__ alignas(16) u16 Xsm[128 * 256];   // 64 KB: X, then G in place
    __shared__ alignas(16) u16 Wsm[1024 * 8];    // 16 KB: [4][256][8] k-tile
    int t = threadIdx.x, lane = t & 63;
    int wv = t >> 6, rowhalf = wv >> 2, chslab = (wv & 3) * 64;
    int arow = lane & 15, kgrp = lane >> 4;
    int p0 = blockIdx.x * 128;
    // ---- stage X panel (swizzle: stored chunk = src chunk ^ (row&7)) ----
#pragma unroll
    for (int i = 0; i < 8; ++i) {
        int d = t + i * 512;
        int row = d >> 5, chunk = d & 31;
        gload16(A + (size_t)(p0 + row) * 256 + ((chunk ^ (row & 7)) * 8),
                &Xsm[d * 8]);
    }
    f32x4 zero = {0.f, 0.f, 0.f, 0.f};
    f32x4 acc[4][4];
#pragma unroll
    for (int a = 0; a < 4; ++a)
#pragma unroll
        for (int b = 0; b < 4; ++b) acc[a][b] = zero;
    // ---- val GEMM (swapped: lane quad = 4 consecutive channels) ----
    for (int k0 = 0; k0 < 256; k0 += 32) {
        __syncthreads();
        gload16(WvP + k0 * 256 + t * 8, &Wsm[t * 8]);
        gload16(WvP + k0 * 256 + (t + 512) * 8, &Wsm[(t + 512) * 8]);
        __syncthreads();
        bf16x8 wf[4], xf[4];
#pragma unroll
        for (int wi = 0; wi < 4; ++wi)
            wf[wi] = *(const bf16x8*)&Wsm[kgrp * 2048 + (chslab + wi * 16 + arow) * 8];
#pragma unroll
        for (int xi = 0; xi < 4; ++xi) {
            int p = rowhalf * 64 + xi * 16 + arow;
            xf[xi] = *(const bf16x8*)&Xsm[p * 256 + (((k0 >> 3) + kgrp) ^ (p & 7)) * 8];
        }
#pragma unroll
        for (int wi = 0; wi < 4; ++wi)
#pragma unroll
            for (int xi = 0; xi < 4; ++xi)
                acc[wi][xi] = __builtin_amdgcn_mfma_f32_16x16x32_bf16(
                    wf[wi], xf[xi], acc[wi][xi], 0, 0, 0);
    }
    __syncthreads();
    // ---- gate in place: Xsm <- G = X + sigmoid(val+bv)*ctx ----
#pragma unroll
    for (int wi = 0; wi < 4; ++wi) {
        int ch = chslab + wi * 16 + kgrp * 4;
        f32x4 bq = *(const f32x4*)&bv[ch];
        f32x4 cx0;
        if (AXIS == 0)
            cx0 = *(const f32x4*)&ctx[(size_t)((p0 >> 6) + rowhalf) * 256 + ch];
#pragma unroll
        for (int xi = 0; xi < 4; ++xi) {
            int row = rowhalf * 64 + xi * 16 + arow;
            f32x4 cx;
            if (AXIS == 0) {
                cx = cx0;
            } else {
                int pg = p0 + row;
                int line = ((pg >> 12) << 6) + (pg & 63);
                cx = *(const f32x4*)&ctx[(size_t)line * 256 + ch];
            }
            int idx = row * 256 + (((ch >> 3) ^ (row & 7)) * 8) + (ch & 7);
            ushort4 xv = *(const ushort4*)&Xsm[idx];
            ushort4 o;
            o.x = f2bf(bf2f(xv.x) + sigm(acc[wi][xi][0] + bq[0]) * cx[0]);
            o.y = f2bf(bf2f(xv.y) + sigm(acc[wi][xi][1] + bq[1]) * cx[1]);
            o.z = f2bf(bf2f(xv.z) + sigm(acc[wi][xi][2] + bq[2]) * cx[2]);
            o.w = f2bf(bf2f(xv.w) + sigm(acc[wi][xi][3] + bq[3]) * cx[3]);
            *(ushort4*)&Xsm[idx] = o;
        }
    }
    // ---- fusion GEMM over G (in LDS) ----
#pragma unroll
    for (int a = 0; a < 4; ++a)
#pragma unroll
        for (int b = 0; b < 4; ++b) acc[a][b] = zero;
    for (int k0 = 0; k0 < 256; k0 += 32) {
        __syncthreads();
        gload16(WfP + k0 * 256 + t * 8, &Wsm[t * 8]);
        gload16(WfP + k0 * 256 + (t + 512) * 8, &Wsm[(t + 512) * 8]);
        __syncthreads();
        bf16x8 wf[4], gf[4];
#pragma unroll
        for (int wi = 0; wi < 4; ++wi)
            wf[wi] = *(const bf16x8*)&Wsm[kgrp * 2048 + (chslab + wi * 16 + arow) * 8];
#pragma unroll
        for (int xi = 0; xi < 4; ++xi) {
            int p = rowhalf * 64 + xi * 16 + arow;
            gf[xi] = *(const bf16x8*)&Xsm[p * 256 + (((k0 >> 3) + kgrp) ^ (p & 7)) * 8];
        }
        if (MODE == 1) {
#pragma unroll
            for (int wi = 0; wi < 4; ++wi)
#pragma unroll
                for (int xi = 0; xi < 4; ++xi)
                    acc[wi][xi] = __builtin_amdgcn_mfma_f32_16x16x32_bf16(
                        wf[wi], gf[xi], acc[wi][xi], 0, 0, 0);
        } else {
#pragma unroll
            for (int xi = 0; xi < 4; ++xi)
#pragma unroll
                for (int wi = 0; wi < 4; ++wi)
                    acc[xi][wi] = __builtin_amdgcn_mfma_f32_16x16x32_bf16(
                        gf[xi], wf[wi], acc[xi][wi], 0, 0, 0);
        }
    }
    // ---- store ----
    if (MODE == 1) {
#pragma unroll
        for (int wi = 0; wi < 4; ++wi) {
            int ch = chslab + wi * 16 + kgrp * 4;
            f32x4 bq = *(const f32x4*)&bfb[ch];
#pragma unroll
            for (int xi = 0; xi < 4; ++xi) {
                int row = rowhalf * 64 + xi * 16 + arow;
                ushort4 o;
                o.x = f2bf(acc[wi][xi][0] + bq[0]);
                o.y = f2bf(acc[wi][xi][1] + bq[1]);
                o.z = f2bf(acc[wi][xi][2] + bq[2]);
                o.w = f2bf(acc[wi][xi][3] + bq[3]);
                *(ushort4*)(bOut + (size_t)(p0 + row) * 256 + ch) = o;
            }
        }
    } else {
        int bb = p0 >> 12;
#pragma unroll
        for (int mi = 0; mi < 4; ++mi) {
            int row0 = rowhalf * 64 + mi * 16 + kgrp * 4;
#pragma unroll
            for (int ni = 0; ni < 4; ++ni) {
                int ch = chslab + ni * 16 + arow;
                float bc = bfb[ch];
                f32x4 v = acc[mi][ni];
                v[0] += bc; v[1] += bc; v[2] += bc; v[3] += bc;
                *(f32x4*)&fOut[((size_t)(bb * 256 + ch)) * 4096 +
                               ((p0 + row0) & 4095)] = v;
            }
        }
    }
}

// ---------------- host ----------------
extern "C" void kernel_launch(void* const* d_in, const int* in_sizes, int n_in,
                              void* d_out, int out_size, void* d_ws, size_t ws_size,
                              hipStream_t stream) {
    const float* x   = (const float*)d_in[0];
    const float* qWw = (const float*)d_in[1];
    const float* qWb = (const float*)d_in[2];
    const float* qHw = (const float*)d_in[3];
    const float* qHb = (const float*)d_in[4];
    const float* fWw = (const float*)d_in[5];
    const float* fWb = (const float*)d_in[6];
    const float* fHw = (const float*)d_in[7];
    const float* fHb = (const float*)d_in[8];
    float* out = (float*)d_out;

    char* ws = (char*)d_ws;
    size_t off = 0;
    auto carve = [&](size_t bytes) -> void* {
        off = (off + 255) & ~(size_t)255;
        void* p = ws + off;
        off += bytes;
        return p;
    };
    const size_t P = 65536;
    u16*   xp   = (u16*)carve(P * 256 * 2);   // x'
    u16*   vb   = (u16*)carve(P * 256 * 2);   // x_w'
    float* ctxb = (float*)carve(1024 * 256 * 4);
    float* wq01  = (float*)carve(256 * 4);
    u16*   wkvK1 = (u16*)carve(256 * 256 * 2);
    u16*   wkvV1 = (u16*)carve(256 * 256 * 2);
    float* bkv1  = (float*)carve(512 * 4);
    u16*   wfP1  = (u16*)carve(65536 * 2);
    float* bff1  = (float*)carve(256 * 4);
    float* wq02  = (float*)carve(256 * 4);
    u16*   wkvK2 = (u16*)carve(256 * 256 * 2);
    u16*   wkvV2 = (u16*)carve(256 * 256 * 2);
    float* bkv2  = (float*)carve(512 * 4);
    u16*   wfP2  = (u16*)carve(65536 * 2);
    float* bff2  = (float*)carve(256 * 4);

    prep_w<<<513, 256, 0, stream>>>(qWw, qWb, fWw, fWb, wq01, wkvK1, wkvV1,
                                    bkv1, wfP1, bff1);
    prep_w<<<513, 256, 0, stream>>>(qHw, qHb, fHw, fHb, wq02, wkvK2, wkvV2,
                                    bkv2, wfP2, bff2);
    transpose_in<<<4096, 256, 0, stream>>>(x, xp);

    // ---- stage 1 (axis = W) ----
    line_ctx<0><<<1024, 256, 0, stream>>>(xp, wkvK1, wq01, bkv1, ctxb);
    fused_stage<0, 1><<<512, 512, 0, stream>>>(xp, wkvV1, bkv1 + 256, wfP1,
                                               bff1, ctxb, vb, nullptr);
    // ---- stage 2 (axis = H) ----
    line_ctx<1><<<1024, 256, 0, stream>>>(vb, wkvK2, wq02, bkv2, ctxb);
    fused_stage<1, 2><<<512, 512, 0, stream>>>(vb, wkvV2, bkv2 + 256, wfP2,
                                               bff2, ctxb, nullptr, out);
    (void)in_sizes; (void)n_in; (void)out_size; (void)ws_size;
}